// Round 1
// baseline (219.455 us; speedup 1.0000x reference)
//
#include <hip/hip_runtime.h>
#include <hip/hip_bf16.h>
#include <stdint.h>

typedef __attribute__((ext_vector_type(8))) short short8;
typedef __attribute__((ext_vector_type(4))) float f32x4;

#define NROWS  8192
#define DDIM   256
#define HHEADS 4
#define KTOT   1024   // H * D
#define BM     128
#define BN     128
#define BK     64
#define KSTEPS (KTOT / BK)   // 16

// round-to-nearest-even float -> bf16 bits
__device__ __forceinline__ unsigned short f2bf(float f) {
  union { float f; uint32_t u; } v;
  v.f = f;
  uint32_t u = v.u;
  uint32_t r = (u + 0x7fffu + ((u >> 16) & 1u)) >> 16;
  return (unsigned short)r;
}

// --------------------------------------------------------------------------
// Kernel 1: Y[n, h*256+d] = bf16( a[h,d]*x[n,d] * rsqrt(max(sum_d (a*x)^2, eps)) )
// one block (256 threads = 4 waves) per row n
// --------------------------------------------------------------------------
__global__ __launch_bounds__(256) void prep_y(const float* __restrict__ x,
                                              const float* __restrict__ av,
                                              unsigned short* __restrict__ Y) {
  __shared__ float a_sh[HHEADS][DDIM];
  __shared__ float red[4][HHEADS];

  const int t = threadIdx.x;   // 0..255 == d
  #pragma unroll
  for (int h = 0; h < HHEADS; ++h) a_sh[h][t] = av[h * DDIM + t];
  __syncthreads();

  const int n = blockIdx.x;
  const float xd = x[(size_t)n * DDIM + t];

  float p[HHEADS], s[HHEADS];
  #pragma unroll
  for (int h = 0; h < HHEADS; ++h) {
    p[h] = a_sh[h][t] * xd;
    s[h] = p[h] * p[h];
  }

  // wave (64-lane) butterfly reduce
  #pragma unroll
  for (int off = 32; off > 0; off >>= 1) {
    #pragma unroll
    for (int h = 0; h < HHEADS; ++h) s[h] += __shfl_xor(s[h], off, 64);
  }

  const int wave = t >> 6, lane = t & 63;
  if (lane == 0) {
    #pragma unroll
    for (int h = 0; h < HHEADS; ++h) red[wave][h] = s[h];
  }
  __syncthreads();

  #pragma unroll
  for (int h = 0; h < HHEADS; ++h) {
    const float sum = red[0][h] + red[1][h] + red[2][h] + red[3][h];
    const float rn = rsqrtf(fmaxf(sum, 1e-12f));
    Y[(size_t)n * KTOT + h * DDIM + t] = f2bf(p[h] * rn);
  }
}

// --------------------------------------------------------------------------
// Kernel 2: C = Y * Y^T / 4   (M=N=8192, K=1024, bf16 in, f32 out)
// 128x128 tile, BK=64, 4 waves (2x2), 16x16x32 bf16 MFMA, 4x4 acc/wave.
// Staging: global_load_lds width=16, LINEAR LDS dest + inverse-swizzled
// GLOBAL source (rule #21).  ds_read_b128 with slot ^= (row&7) swizzle (G4).
// --------------------------------------------------------------------------
__global__ __launch_bounds__(256) void gemm_yyt(const unsigned short* __restrict__ Y,
                                                float* __restrict__ C) {
  __shared__ __attribute__((aligned(16))) unsigned short As[BM * BK];  // 16 KB
  __shared__ __attribute__((aligned(16))) unsigned short Bs[BN * BK];  // 16 KB

  // bijective XCD swizzle: gridDim.x = 4096, divisible by 8
  const int orig = blockIdx.x;
  const int cpx  = gridDim.x >> 3;                 // 512 per XCD
  const int wgid = (orig & 7) * cpx + (orig >> 3);
  const int bx = wgid & 63;                        // tile col (N/BN = 64)
  const int by = wgid >> 6;                        // tile row

  const int t    = threadIdx.x;
  const int lane = t & 63;
  const int wave = t >> 6;
  const int wr   = wave >> 1;   // 0..1
  const int wc   = wave & 1;    // 0..1

  const int rowA0 = by * BM;
  const int rowB0 = bx * BN;

  f32x4 acc[4][4];
  #pragma unroll
  for (int i = 0; i < 4; ++i)
    #pragma unroll
    for (int j = 0; j < 4; ++j) acc[i][j] = (f32x4){0.f, 0.f, 0.f, 0.f};

  for (int kt = 0; kt < KSTEPS; ++kt) {
    const int k0 = kt * BK;
    __syncthreads();  // previous compute done before LDS overwrite

    // stage A tile: 128 rows x 64 cols bf16 = 16 KB = 4 insts x 256 thr x 16 B
    #pragma unroll
    for (int i = 0; i < 4; ++i) {
      const int s     = i * 256 + t;        // 16B-slot index, linear in LDS
      const int row   = s >> 3;             // 8 slots per 128B row
      const int gslot = (s & 7) ^ (row & 7);  // inverse-swizzled source
      const unsigned short* gsrc = Y + (size_t)(rowA0 + row) * KTOT + k0 + gslot * 8;
      unsigned short* ldst = As + s * 8;
      __builtin_amdgcn_global_load_lds(
          (__attribute__((address_space(1))) void*)gsrc,
          (__attribute__((address_space(3))) void*)ldst, 16, 0, 0);
    }
    // stage B tile (rows of Y at the tile-col base; C = Y * Y^T is NT)
    #pragma unroll
    for (int i = 0; i < 4; ++i) {
      const int s     = i * 256 + t;
      const int row   = s >> 3;
      const int gslot = (s & 7) ^ (row & 7);
      const unsigned short* gsrc = Y + (size_t)(rowB0 + row) * KTOT + k0 + gslot * 8;
      unsigned short* ldst = Bs + s * 8;
      __builtin_amdgcn_global_load_lds(
          (__attribute__((address_space(1))) void*)gsrc,
          (__attribute__((address_space(3))) void*)ldst, 16, 0, 0);
    }
    __syncthreads();  // compiler emits s_waitcnt vmcnt(0) before s_barrier

    #pragma unroll
    for (int ks = 0; ks < 2; ++ks) {   // two K=32 sub-steps per BK=64
      short8 af[4], bfr[4];
      #pragma unroll
      for (int mr = 0; mr < 4; ++mr) {
        const int row  = wr * 64 + mr * 16 + (lane & 15);
        const int slot = (ks * 4 + (lane >> 4)) ^ (row & 7);
        af[mr] = *(const short8*)(As + row * BK + slot * 8);
      }
      #pragma unroll
      for (int nr = 0; nr < 4; ++nr) {
        const int row  = wc * 64 + nr * 16 + (lane & 15);
        const int slot = (ks * 4 + (lane >> 4)) ^ (row & 7);
        bfr[nr] = *(const short8*)(Bs + row * BK + slot * 8);
      }
      #pragma unroll
      for (int mr = 0; mr < 4; ++mr)
        #pragma unroll
        for (int nr = 0; nr < 4; ++nr)
          acc[mr][nr] = __builtin_amdgcn_mfma_f32_16x16x32_bf16(
              af[mr], bfr[nr], acc[mr][nr], 0, 0, 0);
    }
  }

  // epilogue: C/D layout col = lane&15, row = (lane>>4)*4 + r  (m89/m91)
  const int crow0 = rowA0 + wr * 64;
  const int ccol  = rowB0 + wc * 64 + (lane & 15);
  #pragma unroll
  for (int mr = 0; mr < 4; ++mr) {
    #pragma unroll
    for (int nr = 0; nr < 4; ++nr) {
      #pragma unroll
      for (int r = 0; r < 4; ++r) {
        const int row = crow0 + mr * 16 + (lane >> 4) * 4 + r;
        C[(size_t)row * NROWS + ccol + nr * 16] = acc[mr][nr][r] * 0.25f;
      }
    }
  }
}

// --------------------------------------------------------------------------
extern "C" void kernel_launch(void* const* d_in, const int* in_sizes, int n_in,
                              void* d_out, int out_size, void* d_ws, size_t ws_size,
                              hipStream_t stream) {
  (void)in_sizes; (void)n_in; (void)out_size; (void)ws_size;
  const float* x  = (const float*)d_in[0];   // [8192, 256] f32
  const float* av = (const float*)d_in[1];   // [4, 256] f32
  float* C = (float*)d_out;                  // [8192, 8192] f32
  unsigned short* Y = (unsigned short*)d_ws; // [8192, 1024] bf16 (16 MB scratch)

  prep_y<<<NROWS, 256, 0, stream>>>(x, av, Y);
  gemm_yyt<<<(NROWS / BM) * (NROWS / BN), 256, 0, stream>>>(Y, C);
}